// Round 12
// baseline (7637.237 us; speedup 1.0000x reference)
//
#include <hip/hip_runtime.h>
#include <math.h>

#define NN 20000      // nodes
#define NE 320000     // edges
#define BB 2
#define TT 24
#define FI 32
#define HH 128

typedef __attribute__((ext_vector_type(4))) float f32x4;
typedef __attribute__((ext_vector_type(8))) short bf16x8;
typedef __attribute__((ext_vector_type(4))) short s16x4;

// ---------------- fp32 <-> bf16 hi/lo split ----------------
__device__ __forceinline__ void split1(float f, short& hi, short& lo) {
    unsigned u = __float_as_uint(f);
    unsigned short h = (unsigned short)((u + 0x7FFFu + ((u >> 16) & 1u)) >> 16);
    float fh = __uint_as_float((unsigned)h << 16);
    float r = f - fh;
    unsigned v = __float_as_uint(r);
    unsigned short l = (unsigned short)((v + 0x7FFFu + ((v >> 16) & 1u)) >> 16);
    hi = (short)h; lo = (short)l;
}

__device__ __forceinline__ float rec2(short h, short l) {
    return __uint_as_float(((unsigned)(unsigned short)h) << 16)
         + __uint_as_float(((unsigned)(unsigned short)l) << 16);
}

// ---------------- edge_index dtype detection ----------------
// int64 (values < 2^31): every odd int32 word is a zero high-word.
__global__ void k_detect(const int* __restrict__ ei, int* __restrict__ flag) {
    int t = threadIdx.x;  // 64 threads
    int nz = 0;
    for (int i = 0; i < 4; ++i) nz |= (ei[2 * (t + 64 * i) + 1] != 0);
    unsigned long long m = __ballot(nz);
    if (t == 0) flag[0] = (m != 0ull) ? 0 : 1;   // 1 => int64
}

__device__ __forceinline__ int eidx(const int* __restrict__ ei, int i, int f64) {
    return f64 ? ei[2 * i] : ei[i];
}

// ---------------- graph preprocessing ----------------

__global__ void k_deg_count(const int* __restrict__ ei, const float* __restrict__ w,
                            float* __restrict__ deg, int* __restrict__ counts,
                            const int* __restrict__ flag) {
    int e = blockIdx.x * blockDim.x + threadIdx.x;
    if (e >= NE) return;
    int f64 = flag[0];
    int s = eidx(ei, e, f64);
    int d = eidx(ei, NE + e, f64);
    atomicAdd(&deg[s], w[e]);
    atomicAdd(&counts[d], 1);
}

__global__ void k_dinv(const float* __restrict__ deg, float* __restrict__ dinv) {
    int n = blockIdx.x * blockDim.x + threadIdx.x;
    if (n >= NN) return;
    float d = deg[n];
    dinv[n] = d > 0.f ? rsqrtf(d) : 0.f;
}

__global__ void k_norm(const int* __restrict__ ei, const float* __restrict__ w,
                       const float* __restrict__ dinv, float* __restrict__ normv,
                       const int* __restrict__ flag) {
    int e = blockIdx.x * blockDim.x + threadIdx.x;
    if (e >= NE) return;
    int f64 = flag[0];
    normv[e] = -dinv[eidx(ei, e, f64)] * w[e] * dinv[eidx(ei, NE + e, f64)];
}

// single-block exclusive scan of counts[NN] -> rowptr[NN+1]
__global__ void k_scan(const int* __restrict__ counts, int* __restrict__ rowptr) {
    __shared__ int sums[1024];
    int t = threadIdx.x;
    const int CH = (NN + 1023) / 1024;
    int start = t * CH;
    int s = 0;
    for (int i = 0; i < CH; ++i) {
        int idx = start + i;
        if (idx < NN) s += counts[idx];
    }
    sums[t] = s;
    __syncthreads();
    for (int off = 1; off < 1024; off *= 2) {
        int v = (t >= off) ? sums[t - off] : 0;
        __syncthreads();
        sums[t] += v;
        __syncthreads();
    }
    int run = (t > 0) ? sums[t - 1] : 0;
    for (int i = 0; i < CH; ++i) {
        int idx = start + i;
        if (idx < NN) { rowptr[idx] = run; run += counts[idx]; }
    }
    if (t == 1023) rowptr[NN] = sums[1023];
}

__global__ void k_copy_int(const int* __restrict__ src, int* __restrict__ dst, int n) {
    int i = blockIdx.x * blockDim.x + threadIdx.x;
    if (i < n) dst[i] = src[i];
}

__global__ void k_fill(const int* __restrict__ ei, const float* __restrict__ normv,
                       int* __restrict__ cursor, int* __restrict__ col, float* __restrict__ val,
                       const int* __restrict__ flag) {
    int e = blockIdx.x * blockDim.x + threadIdx.x;
    if (e >= NE) return;
    int f64 = flag[0];
    int d = eidx(ei, NE + e, f64);
    int p = atomicAdd(&cursor[d], 1);
    col[p] = eidx(ei, e, f64);
    val[p] = normv[e];
}

// ---------------- per-step SpMM + split (x side) ----------------
// block = node n, 64 threads (f = lane&31, b = lane>>5).
__global__ void k_prop_x_split(const float* __restrict__ x_seq, int t,
                               const int* __restrict__ rowptr, const int* __restrict__ col,
                               const float* __restrict__ val,
                               short* __restrict__ pxhi, short* __restrict__ pxlo,
                               short* __restrict__ xhi, short* __restrict__ xlo) {
    int n = blockIdx.x;
    int f = threadIdx.x & 31;
    int b = threadIdx.x >> 5;
    int beg = rowptr[n], end = rowptr[n + 1];
    const float* xb = x_seq + ((long)(b * TT + t) * NN) * FI;
    float acc = 0.f;
    for (int j = beg; j < end; ++j)
        acc += val[j] * xb[(long)col[j] * FI + f];
    long o = ((long)b * NN + n) * FI + f;
    short h, l;
    split1(acc, h, l);
    pxhi[o] = h; pxlo[o] = l;
    split1(xb[(long)n * FI + f], h, l);
    xhi[o] = h; xlo[o] = l;
}

// ---------------- SpMM + split (h side), input = split pair planes ----------------
// 256 threads = 4 waves = 4 nodes; lanes 0-31 -> b=0, 32-63 -> b=1; lane covers 4 cols.
__global__ void k_prop_h_split(const short* __restrict__ hi_in, const short* __restrict__ lo_in,
                               const int* __restrict__ rowptr, const int* __restrict__ col,
                               const float* __restrict__ val,
                               short* __restrict__ phi, short* __restrict__ plo) {
    int lane = threadIdx.x & 63;
    int n = blockIdx.x * 4 + (threadIdx.x >> 6);
    int b = lane >> 5;
    int c4 = (lane & 31) << 2;
    int beg = rowptr[n], end = rowptr[n + 1];
    const short* hb = hi_in + (long)b * NN * HH + c4;
    const short* lb = lo_in + (long)b * NN * HH + c4;
    f32x4 acc = {0.f, 0.f, 0.f, 0.f};
    for (int j = beg; j < end; ++j) {
        float v = val[j];
        long ro = (long)col[j] * HH;
        s16x4 qh = *(const s16x4*)(hb + ro);
        s16x4 ql = *(const s16x4*)(lb + ro);
#pragma unroll
        for (int i = 0; i < 4; ++i)
            acc[i] += v * rec2(qh[i], ql[i]);
    }
    long o = ((long)b * NN + n) * HH + c4;
    s16x4 hv, lv;
#pragma unroll
    for (int i = 0; i < 4; ++i) {
        short h, l;
        split1(acc[i], h, l);
        hv[i] = h; lv[i] = l;
    }
    *(s16x4*)(phi + o) = hv;
    *(s16x4*)(plo + o) = lv;
}

// ---------------- weight prep: combined [320][128] -> transposed bf16 hi/lo [128][320] ----
// combined row k: k<64 -> Wx[k][c] ([2][din][128] flat); else Wh[k-64][c].
__global__ void k_prep_w(const float* __restrict__ Wx, const float* __restrict__ Wh,
                         short* __restrict__ hi, short* __restrict__ lo) {
    int idx = blockIdx.x * blockDim.x + threadIdx.x;   // c*320 + k
    if (idx >= HH * 320) return;
    int c = idx / 320, k = idx - c * 320;
    float w = (k < 2 * FI) ? Wx[k * HH + c] : Wh[(k - 2 * FI) * HH + c];
    short h, l;
    split1(w, h, l);
    hi[idx] = h; lo[idx] = l;
}

// ---------------- MFMA split-bf16 quad-input GEMM ----------------
// v = [x | px | ah | aph] @ W + bx + bh   (K = 320, N = 128), all A planar bf16 hi/lo.
// Block: 16 rows x 128 cols, 128 threads = 2 waves; wave w covers cols w*64.
// Wave tile: 1(m) x 4(n) fragments of 16x16; K-loop 10 steps of 32.
// 4-term split product: ah*wh + ah*wl + al*wh + al*wl (exact within fp32 accum).
// EPI 1 (gate-merged): gate0 = z (W0), gate1 = r (W1).
//   z = sigmoid(v0) -> o0 pair; hr = sigmoid(v1) * rec(hc) -> o1 pair.
// EPI 2: ht = tanh(v0); hn = rec(zin)*rec(hc) + (1-rec(zin))*ht -> o0 pair (in-place h).
template<int EPI>
__global__ __launch_bounds__(128)
void k_gemm_mfma(const short* __restrict__ xhi, const short* __restrict__ xlo,
                 const short* __restrict__ pxhi, const short* __restrict__ pxlo,
                 const short* __restrict__ ahhi, const short* __restrict__ ahlo,
                 const short* __restrict__ aphi, const short* __restrict__ aplo,
                 const short* __restrict__ Whi0, const short* __restrict__ Wlo0,
                 const float* __restrict__ bx0, const float* __restrict__ bh0,
                 const short* __restrict__ Whi1, const short* __restrict__ Wlo1,
                 const float* __restrict__ bx1, const float* __restrict__ bh1,
                 const short* __restrict__ hchi, const short* __restrict__ hclo,
                 const short* __restrict__ zhi_in, const short* __restrict__ zlo_in,
                 short* __restrict__ o0hi, short* __restrict__ o0lo,
                 short* __restrict__ o1hi, short* __restrict__ o1lo) {
    const int tid = threadIdx.x;
    const int lane = tid & 63;
    const int wid = tid >> 6;        // 0..1
    const int lr = lane & 15;        // A row / W col / D col
    const int lg = lane >> 4;        // k-group (0..3)

    const int row_base = blockIdx.x * 16;
    const int col_base = wid * 64;
    const int row = row_base + lr;
    const long r32  = (long)row * FI + lg * 8;
    const long r128 = (long)row * HH + lg * 8;
    const long wb = (long)(col_base + lr) * 320;

    f32x4 acc0[4], acc1[4];
#pragma unroll
    for (int n = 0; n < 4; ++n) {
        acc0[n] = (f32x4){0.f, 0.f, 0.f, 0.f};
        acc1[n] = (f32x4){0.f, 0.f, 0.f, 0.f};
    }

#pragma unroll
    for (int ks = 0; ks < 10; ++ks) {
        const short *ph_, *pl_;
        long off;
        if (ks == 0)      { ph_ = xhi;  pl_ = xlo;  off = r32; }
        else if (ks == 1) { ph_ = pxhi; pl_ = pxlo; off = r32; }
        else if (ks < 6)  { ph_ = ahhi; pl_ = ahlo; off = r128 + (ks - 2) * 32; }
        else              { ph_ = aphi; pl_ = aplo; off = r128 + (ks - 6) * 32; }
        bf16x8 ahi = *(const bf16x8*)(ph_ + off);
        bf16x8 alo = *(const bf16x8*)(pl_ + off);
#pragma unroll
        for (int n = 0; n < 4; ++n) {
            const long wo = wb + (long)n * (16 * 320) + ks * 32 + lg * 8;
            bf16x8 wh0 = *(const bf16x8*)(Whi0 + wo);
            bf16x8 wl0 = *(const bf16x8*)(Wlo0 + wo);
            acc0[n] = __builtin_amdgcn_mfma_f32_16x16x32_bf16(ahi, wh0, acc0[n], 0, 0, 0);
            acc0[n] = __builtin_amdgcn_mfma_f32_16x16x32_bf16(ahi, wl0, acc0[n], 0, 0, 0);
            acc0[n] = __builtin_amdgcn_mfma_f32_16x16x32_bf16(alo, wh0, acc0[n], 0, 0, 0);
            acc0[n] = __builtin_amdgcn_mfma_f32_16x16x32_bf16(alo, wl0, acc0[n], 0, 0, 0);
            if (EPI == 1) {
                bf16x8 wh1 = *(const bf16x8*)(Whi1 + wo);
                bf16x8 wl1 = *(const bf16x8*)(Wlo1 + wo);
                acc1[n] = __builtin_amdgcn_mfma_f32_16x16x32_bf16(ahi, wh1, acc1[n], 0, 0, 0);
                acc1[n] = __builtin_amdgcn_mfma_f32_16x16x32_bf16(ahi, wl1, acc1[n], 0, 0, 0);
                acc1[n] = __builtin_amdgcn_mfma_f32_16x16x32_bf16(alo, wh1, acc1[n], 0, 0, 0);
                acc1[n] = __builtin_amdgcn_mfma_f32_16x16x32_bf16(alo, wl1, acc1[n], 0, 0, 0);
            }
        }
    }

    // epilogue: D col = lane&15, row = (lane>>4)*4 + reg  [m89/m91 verified]
#pragma unroll
    for (int n = 0; n < 4; ++n) {
        const int col = col_base + n * 16 + lr;
        const float b0 = bx0[col] + bh0[col];
        const float b1 = (EPI == 1) ? (bx1[col] + bh1[col]) : 0.f;
#pragma unroll
        for (int j = 0; j < 4; ++j) {
            const int ro = row_base + lg * 4 + j;
            const long o = (long)ro * HH + col;
            short hh, ll;
            if (EPI == 1) {
                float z = 1.f / (1.f + expf(-(acc0[n][j] + b0)));
                split1(z, hh, ll);
                o0hi[o] = hh; o0lo[o] = ll;                 // z pair
                float r = 1.f / (1.f + expf(-(acc1[n][j] + b1)));
                float h = rec2(hchi[o], hclo[o]);
                split1(r * h, hh, ll);
                o1hi[o] = hh; o1lo[o] = ll;                 // h*r pair
            } else {
                float ht = tanhf(acc0[n][j] + b0);
                float z = rec2(zhi_in[o], zlo_in[o]);
                float h = rec2(hchi[o], hclo[o]);
                float hn = z * h + (1.f - z) * ht;          // new h
                split1(hn, hh, ll);
                o0hi[o] = hh; o0lo[o] = ll;                 // h pair (in place)
            }
        }
    }
}

// ---------------- output head ----------------
__global__ void k_out(const short* __restrict__ hhi, const short* __restrict__ hlo,
                      const float* __restrict__ Wl, const float* __restrict__ bl,
                      float* __restrict__ out) {
    int row = blockIdx.x;        // 0 .. B*NN-1
    int lane = threadIdx.x;      // 64
    long base = (long)row * HH;
    float a = fmaxf(rec2(hhi[base + lane], hlo[base + lane]), 0.f) * Wl[lane]
            + fmaxf(rec2(hhi[base + 64 + lane], hlo[base + 64 + lane]), 0.f) * Wl[64 + lane];
#pragma unroll
    for (int off = 32; off > 0; off >>= 1) a += __shfl_down(a, off);
    if (lane == 0) out[row] = a + bl[0];
}

// ---------------- launcher ----------------
extern "C" void kernel_launch(void* const* d_in, const int* in_sizes, int n_in,
                              void* d_out, int out_size, void* d_ws, size_t ws_size,
                              hipStream_t stream) {
    const float* x_seq = (const float*)d_in[0];
    const int*   ei    = (const int*)d_in[1];
    const float* ew    = (const float*)d_in[2];
    const float* Wxz = (const float*)d_in[3],  *bxz = (const float*)d_in[4];
    const float* Whz = (const float*)d_in[5],  *bhz = (const float*)d_in[6];
    const float* Wxr = (const float*)d_in[7],  *bxr = (const float*)d_in[8];
    const float* Whr = (const float*)d_in[9],  *bhr = (const float*)d_in[10];
    const float* Wxh = (const float*)d_in[11], *bxh = (const float*)d_in[12];
    const float* Whh = (const float*)d_in[13], *bhh = (const float*)d_in[14];
    const float* Wl  = (const float*)d_in[15], *bl  = (const float*)d_in[16];
    float* out = (float*)d_out;

    char* p = (char*)d_ws;
    auto alloc = [&](size_t bytes) -> char* {
        char* r = p;
        p += (bytes + 255) & ~(size_t)255;
        return r;
    };
    const long RB = (long)BB * NN;  // 40000 rows

    int*   dflag  = (int*)alloc(4);
    float* deg    = (float*)alloc(NN * 4);
    float* dinv   = (float*)alloc(NN * 4);
    float* normv  = (float*)alloc(NE * 4);
    int*   counts = (int*)alloc(NN * 4);
    int*   rowptr = (int*)alloc((NN + 1) * 4);
    int*   cursor = (int*)alloc(NN * 4);
    int*   ccol   = (int*)alloc(NE * 4);
    float* cval   = (float*)alloc(NE * 4);
    short* xthi   = (short*)alloc(RB * FI * 2);   // x_t pair
    short* xtlo   = (short*)alloc(RB * FI * 2);
    short* pxhi   = (short*)alloc(RB * FI * 2);   // Ltilde@x_t pair
    short* pxlo   = (short*)alloc(RB * FI * 2);
    short* hhi    = (short*)alloc(RB * HH * 2);   // h pair (the ONLY h storage)
    short* hlo    = (short*)alloc(RB * HH * 2);
    short* hrhi   = (short*)alloc(RB * HH * 2);   // h*r pair
    short* hrlo   = (short*)alloc(RB * HH * 2);
    short* phhi   = (short*)alloc(RB * HH * 2);   // Ltilde@h / Ltilde@(h*r) pair
    short* phlo   = (short*)alloc(RB * HH * 2);
    short* zhi    = (short*)alloc(RB * HH * 2);   // z pair
    short* zlo    = (short*)alloc(RB * HH * 2);
    short* WtZhi  = (short*)alloc(HH * 320 * 2);
    short* WtZlo  = (short*)alloc(HH * 320 * 2);
    short* WtRhi  = (short*)alloc(HH * 320 * 2);
    short* WtRlo  = (short*)alloc(HH * 320 * 2);
    short* WtHhi  = (short*)alloc(HH * 320 * 2);
    short* WtHlo  = (short*)alloc(HH * 320 * 2);

    // graph preprocessing
    hipMemsetAsync(deg, 0, NN * 4, stream);
    hipMemsetAsync(counts, 0, NN * 4, stream);
    k_detect<<<1, 64, 0, stream>>>(ei, dflag);
    k_deg_count<<<(NE + 255) / 256, 256, 0, stream>>>(ei, ew, deg, counts, dflag);
    k_dinv<<<(NN + 255) / 256, 256, 0, stream>>>(deg, dinv);
    k_norm<<<(NE + 255) / 256, 256, 0, stream>>>(ei, ew, dinv, normv, dflag);
    k_scan<<<1, 1024, 0, stream>>>(counts, rowptr);
    k_copy_int<<<(NN + 255) / 256, 256, 0, stream>>>(rowptr, cursor, NN);
    k_fill<<<(NE + 255) / 256, 256, 0, stream>>>(ei, normv, cursor, ccol, cval, dflag);

    // weight prep (transposed bf16 hi/lo)
    const int WPE = HH * 320;
    k_prep_w<<<(WPE + 255) / 256, 256, 0, stream>>>(Wxz, Whz, WtZhi, WtZlo);
    k_prep_w<<<(WPE + 255) / 256, 256, 0, stream>>>(Wxr, Whr, WtRhi, WtRlo);
    k_prep_w<<<(WPE + 255) / 256, 256, 0, stream>>>(Wxh, Whh, WtHhi, WtHlo);

    // h0 = 0 (pair)
    hipMemsetAsync(hhi, 0, RB * HH * 2, stream);
    hipMemsetAsync(hlo, 0, RB * HH * 2, stream);

    dim3 g(2500);   // 40000 rows / 16 per block
    for (int t = 0; t < TT; ++t) {
        // x-side SpMM + x_t/px pairs (per-step slab, cache-hot)
        k_prop_x_split<<<NN, 64, 0, stream>>>(x_seq, t, rowptr, ccol, cval,
                                              pxhi, pxlo, xthi, xtlo);
        // ph = Ltilde @ h (pair in, pair out)
        k_prop_h_split<<<NN / 4, 256, 0, stream>>>(hhi, hlo, rowptr, ccol, cval, phhi, phlo);
        // gate-merged z/r: z pair -> zhi/zlo ; hr = sigmoid(r)*h pair -> hrhi/hrlo
        k_gemm_mfma<1><<<g, 128, 0, stream>>>(
            xthi, xtlo, pxhi, pxlo, hhi, hlo, phhi, phlo,
            WtZhi, WtZlo, bxz, bhz, WtRhi, WtRlo, bxr, bhr,
            hhi, hlo, nullptr, nullptr,
            zhi, zlo, hrhi, hrlo);
        // phr = Ltilde @ (h*r)
        k_prop_h_split<<<NN / 4, 256, 0, stream>>>(hrhi, hrlo, rowptr, ccol, cval, phhi, phlo);
        // candidate + GRU update: h = z*h + (1-z)*tanh(...)  (in-place h pair)
        k_gemm_mfma<2><<<g, 128, 0, stream>>>(
            xthi, xtlo, pxhi, pxlo, hrhi, hrlo, phhi, phlo,
            WtHhi, WtHlo, bxh, bhh, nullptr, nullptr, nullptr, nullptr,
            hhi, hlo, zhi, zlo,
            hhi, hlo, nullptr, nullptr);
    }

    // out = relu(h) @ Wl + bl
    k_out<<<RB, 64, 0, stream>>>(hhi, hlo, Wl, bl, out);
}